// Round 1
// baseline (334.451 us; speedup 1.0000x reference)
//
#include <hip/hip_runtime.h>
#include <math.h>

// SSIM loss, fp32, B=64, H=W=512, 11x11 Gaussian sigma=1.5 (separable).
// Tile: 32x32 outputs per block, halo 5 each side (42x42 raw tile).
// Stage 1: load x,y raw tiles -> LDS (row stride padded to 44 for 16B-aligned rows)
// Stage 2: horizontal 11-tap conv of {x, y, x^2, y^2, xy} -> 5 LDS arrays [42][32]
// Stage 3: vertical 11-tap conv + SSIM formula + block reduction -> atomicAdd
// Finalize: out = 1 - acc / (64*512*512)

#define TS   32
#define HALO 5
#define IN   42          // TS + 2*HALO
#define SXW  44          // padded raw row stride: 44*4B = 176B = 11*16B (16B aligned rows)

struct W11 { float w[11]; };

__global__ __launch_bounds__(64) void ssim_zero(float* __restrict__ acc) {
    if (threadIdx.x == 0) acc[0] = 0.f;
}

__global__ __launch_bounds__(256) void ssim_main(
    const float* __restrict__ x, const float* __restrict__ y,
    float* __restrict__ acc, W11 wk)
{
    __shared__ __align__(16) float sx[IN * SXW];
    __shared__ __align__(16) float sy[IN * SXW];
    __shared__ __align__(16) float h[5][IN * TS];
    __shared__ float red[4];

    const int tid = threadIdx.x;
    const int ix0 = blockIdx.x * TS - HALO;
    const int iy0 = blockIdx.y * TS - HALO;
    const float* __restrict__ xb = x + (size_t)blockIdx.z * (512 * 512);
    const float* __restrict__ yb = y + (size_t)blockIdx.z * (512 * 512);

    // ---- stage 1: raw tiles (zero-padded at image edges) ----
    for (int i = tid; i < IN * SXW; i += 256) {
        int r = i / SXW, c = i - r * SXW;
        float vx = 0.f, vy = 0.f;
        int gr = iy0 + r, gc = ix0 + c;
        if (c < IN && (unsigned)gr < 512u && (unsigned)gc < 512u) {
            int idx = gr * 512 + gc;
            vx = xb[idx];
            vy = yb[idx];
        }
        sx[i] = vx;
        sy[i] = vy;
    }
    __syncthreads();

    // ---- stage 2: horizontal conv, each task does 4 consecutive cols of one row ----
    for (int t = tid; t < IN * 8; t += 256) {
        int r = t >> 3;
        int c0 = (t & 7) * 4;
        const float4* px = (const float4*)(sx + r * SXW + c0);
        const float4* py = (const float4*)(sy + r * SXW + c0);
        float4 a0 = px[0], a1 = px[1], a2 = px[2], a3 = px[3];
        float4 b0 = py[0], b1 = py[1], b2 = py[2], b3 = py[3];
        float rx[16] = {a0.x,a0.y,a0.z,a0.w, a1.x,a1.y,a1.z,a1.w,
                        a2.x,a2.y,a2.z,a2.w, a3.x,a3.y,a3.z,a3.w};
        float ry[16] = {b0.x,b0.y,b0.z,b0.w, b1.x,b1.y,b1.z,b1.w,
                        b2.x,b2.y,b2.z,b2.w, b3.x,b3.y,b3.z,b3.w};
        float hx[4]  = {0.f,0.f,0.f,0.f};
        float hy[4]  = {0.f,0.f,0.f,0.f};
        float hxx[4] = {0.f,0.f,0.f,0.f};
        float hyy[4] = {0.f,0.f,0.f,0.f};
        float hxy[4] = {0.f,0.f,0.f,0.f};
        #pragma unroll
        for (int j = 0; j < 11; ++j) {
            float wj = wk.w[j];
            #pragma unroll
            for (int o = 0; o < 4; ++o) {
                float xv = rx[o + j], yv = ry[o + j];
                float tx = wj * xv, ty = wj * yv;
                hx[o] += tx;
                hy[o] += ty;
                hxx[o] = fmaf(tx, xv, hxx[o]);
                hyy[o] = fmaf(ty, yv, hyy[o]);
                hxy[o] = fmaf(tx, yv, hxy[o]);
            }
        }
        int ho = r * TS + c0;
        *(float4*)&h[0][ho] = make_float4(hx[0],  hx[1],  hx[2],  hx[3]);
        *(float4*)&h[1][ho] = make_float4(hy[0],  hy[1],  hy[2],  hy[3]);
        *(float4*)&h[2][ho] = make_float4(hxx[0], hxx[1], hxx[2], hxx[3]);
        *(float4*)&h[3][ho] = make_float4(hyy[0], hyy[1], hyy[2], hyy[3]);
        *(float4*)&h[4][ho] = make_float4(hxy[0], hxy[1], hxy[2], hxy[3]);
    }
    __syncthreads();

    // ---- stage 3: vertical conv (4 stacked rows per thread) + SSIM ----
    const int c  = tid & 31;
    const int r0 = (tid >> 5) * 4;
    float s[5][4];
    #pragma unroll
    for (int q = 0; q < 5; ++q) {
        float t[14];
        #pragma unroll
        for (int k = 0; k < 14; ++k) t[k] = h[q][(r0 + k) * TS + c];
        #pragma unroll
        for (int o = 0; o < 4; ++o) {
            float acc_ = 0.f;
            #pragma unroll
            for (int j = 0; j < 11; ++j) acc_ = fmaf(wk.w[j], t[o + j], acc_);
            s[q][o] = acc_;
        }
    }

    const float C1 = 1e-4f, C2 = 9e-4f;
    float lsum = 0.f;
    #pragma unroll
    for (int o = 0; o < 4; ++o) {
        float mx = s[0][o], my = s[1][o];
        float Sxx = s[2][o], Syy = s[3][o], Sxy = s[4][o];
        float mx2 = mx * mx, my2 = my * my, mxy = mx * my;
        float sx2 = Sxx - mx2;
        float sy2 = Syy - my2;
        float sxy = Sxy - mxy;
        float num = (2.f * mxy + C1) * (2.f * sxy + C2);
        float den = (mx2 + my2 + C1) * (sx2 + sy2 + C2) + 1e-12f;
        lsum += num * __builtin_amdgcn_rcpf(den);
    }

    // ---- block reduction ----
    #pragma unroll
    for (int off = 32; off > 0; off >>= 1) lsum += __shfl_down(lsum, off);
    if ((tid & 63) == 0) red[tid >> 6] = lsum;
    __syncthreads();
    if (tid == 0) atomicAdd(acc, red[0] + red[1] + red[2] + red[3]);
}

__global__ __launch_bounds__(64) void ssim_fin(const float* __restrict__ acc,
                                               float* __restrict__ out) {
    if (threadIdx.x == 0) out[0] = 1.0f - acc[0] * (1.0f / 16777216.0f);
}

extern "C" void kernel_launch(void* const* d_in, const int* in_sizes, int n_in,
                              void* d_out, int out_size, void* d_ws, size_t ws_size,
                              hipStream_t stream) {
    const float* x = (const float*)d_in[0];
    const float* y = (const float*)d_in[1];
    float* out = (float*)d_out;
    float* acc = (float*)d_ws;

    // 1D Gaussian weights, sigma=1.5, ks=11, normalized (2D kernel = w ⊗ w)
    W11 wk;
    double e[11], s = 0.0;
    for (int i = 0; i < 11; ++i) {
        double d = (double)i - 5.0;
        e[i] = exp(-(d * d) / 4.5);
        s += e[i];
    }
    for (int i = 0; i < 11; ++i) wk.w[i] = (float)(e[i] / s);

    hipLaunchKernelGGL(ssim_zero, dim3(1), dim3(64), 0, stream, acc);
    hipLaunchKernelGGL(ssim_main, dim3(16, 16, 64), dim3(256), 0, stream, x, y, acc, wk);
    hipLaunchKernelGGL(ssim_fin, dim3(1), dim3(64), 0, stream, acc, out);
}